// Round 13
// baseline (303.781 us; speedup 1.0000x reference)
//
#include <hip/hip_runtime.h>
#include <hip/hip_fp16.h>
#include <math.h>

#define N_NODES 50000
#define N_EDGES 800000
#define E_TOT   850000          // edges + self loops
#define NEG_SLOPE 0.2f
#define NB_SCAN 49              // ceil(N_NODES / 1024)
#define PLANE   (N_NODES * 32)  // halves per 32-channel plane

typedef unsigned short u16;     // N_NODES < 65536: src ids and ranks fit in 16b

// ===========================================================================
// CSR-by-dst construction (once per call; dst indices shared by all 4 layers)
// ===========================================================================
__global__ void csr_init(int* deg) {
    int i = blockIdx.x * blockDim.x + threadIdx.x;
    if (i < N_NODES) deg[i] = 0;
}

__global__ void csr_degree(const int* __restrict__ dst, int* __restrict__ deg,
                           u16* __restrict__ rank) {
    int e = blockIdx.x * blockDim.x + threadIdx.x;
    if (e >= E_TOT) return;
    int d = (e < N_EDGES) ? dst[e] : (e - N_EDGES);
    rank[e] = (u16)atomicAdd(&deg[d], 1);
}

__global__ void scan_p1(const int* __restrict__ deg, int* __restrict__ bsum) {
    __shared__ int red[1024];
    int i = blockIdx.x * 1024 + threadIdx.x;
    red[threadIdx.x] = (i < N_NODES) ? deg[i] : 0;
    __syncthreads();
    for (int off = 512; off >= 1; off >>= 1) {
        if (threadIdx.x < off) red[threadIdx.x] += red[threadIdx.x + off];
        __syncthreads();
    }
    if (threadIdx.x == 0) bsum[blockIdx.x] = red[0];
}

__global__ void scan_p3(const int* __restrict__ deg, const int* __restrict__ bsum,
                        int* __restrict__ offs) {
    __shared__ int s[1024];
    __shared__ int bofs;
    int i = blockIdx.x * 1024 + threadIdx.x;
    int v = (i < N_NODES) ? deg[i] : 0;
    s[threadIdx.x] = v;
    if (threadIdx.x < 64) {
        int d = (threadIdx.x < NB_SCAN) ? bsum[threadIdx.x] : 0;
        int p = d;
        for (int off = 1; off < 64; off <<= 1) {
            int u = __shfl_up(p, off, 64);
            if ((int)threadIdx.x >= off) p += u;
        }
        if ((int)threadIdx.x == (int)blockIdx.x) bofs = p - d;
        if (blockIdx.x == NB_SCAN - 1 && threadIdx.x == NB_SCAN - 1)
            offs[N_NODES] = p;
    }
    __syncthreads();
    for (int off = 1; off < 1024; off <<= 1) {
        int u = (threadIdx.x >= off) ? s[threadIdx.x - off] : 0;
        __syncthreads();
        s[threadIdx.x] += u;
        __syncthreads();
    }
    if (i < N_NODES) offs[i] = bofs + s[threadIdx.x] - v;
}

__global__ void csr_fill(const int* __restrict__ src, const int* __restrict__ dst,
                         const u16* __restrict__ rank, const int* __restrict__ offs,
                         u16* __restrict__ csr_src) {
    int e = blockIdx.x * blockDim.x + threadIdx.x;
    if (e >= E_TOT) return;
    int s, d;
    if (e < N_EDGES) { s = src[e]; d = dst[e]; } else { s = e - N_EDGES; d = s; }
    csr_src[offs[d] + rank[e]] = (u16)s;
}

// ===========================================================================
// Layer-1 GEMM + projections; H written as two 32-channel fp16 planes.
// ===========================================================================
__global__ void gemm_proj(const float* __restrict__ X, const float* __restrict__ W,
                          const float* __restrict__ a_src, const float* __restrict__ a_dst,
                          __half* __restrict__ Hh, float* __restrict__ ssrc,
                          float* __restrict__ sdst) {
    __shared__ float sW[64 * 64];
    __shared__ float sX[16][65];
    const int tid = threadIdx.x;
    for (int i = tid; i < 64 * 64 / 4; i += 256)
        ((float4*)sW)[i] = ((const float4*)W)[i];
    const int base = blockIdx.x * 16;
    for (int i = tid; i < 16 * 64; i += 256) {
        int r = i / 64, col = i % 64;
        int node = base + r;
        sX[r][col] = (node < N_NODES) ? X[(long)node * 64 + col] : 0.0f;
    }
    __syncthreads();
    const int cq = tid % 16;
    const int g  = tid / 16;
    const int node = base + g;
    if (node >= N_NODES) return;
    float ax = 0.0f, ay = 0.0f, az = 0.0f, aw = 0.0f;
    const float4* sW4 = (const float4*)sW;
#pragma unroll
    for (int k = 0; k < 64; k++) {
        float xv = sX[g][k];
        float4 w4 = sW4[k * 16 + cq];
        ax = fmaf(xv, w4.x, ax); ay = fmaf(xv, w4.y, ay);
        az = fmaf(xv, w4.z, az); aw = fmaf(xv, w4.w, aw);
    }
    union { uint2 u; __half2 h2[2]; } pk;
    pk.h2[0] = __float22half2_rn(make_float2(ax, ay));
    pk.h2[1] = __float22half2_rn(make_float2(az, aw));
    __half* dp = (cq < 8) ? Hh + (long)node * 32 + 4 * cq
                          : Hh + PLANE + (long)node * 32 + 4 * cq - 32;
    *(uint2*)dp = pk.u;

    float4 as4 = ((const float4*)a_src)[cq];
    float4 ad4 = ((const float4*)a_dst)[cq];
    float ps = ax * as4.x + ay * as4.y + az * as4.z + aw * as4.w;
    float pd = ax * ad4.x + ay * ad4.y + az * ad4.z + aw * ad4.w;
#pragma unroll
    for (int m = 8; m >= 1; m >>= 1) {
        ps += __shfl_xor(ps, m, 16);
        pd += __shfl_xor(pd, m, 16);
    }
    if (cq == 0) { ssrc[node] = ps; sdst[node] = pd; }
}

// ===========================================================================
// Split-channel 64-dim gather: one dispatch per 32-channel plane (3.2MB ->
// per-XCD-L2-resident). 16 lanes/node, dword (2 halves) per lane = 64B = one
// cache line per edge. HI=1 also runs the fused next-layer GEMM using o_lo
// stored by the HI=0 dispatch.
// ===========================================================================
template<int DOUT, int HI>
__global__ void gather64(const __half* __restrict__ Hplane,
                         const float* __restrict__ ssrc_in,
                         const float* __restrict__ sdst_in,
                         const int* __restrict__ offs,
                         const u16* __restrict__ csr_src,
                         const float* __restrict__ bias_in,
                         int relu_o,
                         float* __restrict__ extra_out,   // [N,64] rows (may be null)
                         float* __restrict__ OL,          // [N,32] fp32 half-output
                         const float* __restrict__ W2,
                         const float* __restrict__ a_src2,
                         const float* __restrict__ a_dst2,
                         __half* __restrict__ Hh_out,
                         float* __restrict__ ssrc2, float* __restrict__ sdst2) {
    constexpr int G = 16;
    constexpr bool DOGEMM = (DOUT > 0) && (HI == 1);
    constexpr int LDSW = DOGEMM ? 64 * DOUT : 1;
    __shared__ float sW[LDSW];
    if constexpr (DOGEMM) {
        for (int i = threadIdx.x; i < 64 * DOUT / 4; i += 256)
            ((float4*)sW)[i] = ((const float4*)W2)[i];
        __syncthreads();
    }
    const int t = threadIdx.x;
    const int node = blockIdx.x * 16 + t / G;    // grid exactly covers N_NODES
    const int r = t % G;
    const int beg = offs[node], end = offs[node + 1];
    const int deg = end - beg;
    const float sdv = sdst_in[node];
    const unsigned int* Hd = (const unsigned int*)Hplane;   // 16 dwords per row

    // headers for chunks 0 and 1 issued together
    int   s0 = 0, s1 = 0;
    float ex0 = 0.0f, ex1 = 0.0f;
    if (r < deg)     s0 = csr_src[beg + r];
    if (G + r < deg) s1 = csr_src[beg + G + r];
    if (r < deg) {
        float v = ssrc_in[s0] + sdv;
        v = (v > 0.0f) ? v : NEG_SLOPE * v;
        ex0 = __expf(v);
    }
    if (G + r < deg) {
        float v = ssrc_in[s1] + sdv;
        v = (v > 0.0f) ? v : NEG_SLOPE * v;
        ex1 = __expf(v);
    }
    float den = ex0 + ex1;
    float2 acc = make_float2(0.0f, 0.0f);

#pragma unroll
    for (int j = 0; j < G; j++) {
        int   sa = __shfl(s0, j, G);
        float ea = __shfl(ex0, j, G);
        unsigned int u = Hd[(long)sa * 16 + r];
        float2 h = __half22float2(*(__half2*)&u);
        acc.x = fmaf(ea, h.x, acc.x); acc.y = fmaf(ea, h.y, acc.y);
    }
    if (deg > G) {
#pragma unroll
        for (int j = 0; j < G; j++) {
            int   sa = __shfl(s1, j, G);
            float ea = __shfl(ex1, j, G);
            unsigned int u = Hd[(long)sa * 16 + r];
            float2 h = __half22float2(*(__half2*)&u);
            acc.x = fmaf(ea, h.x, acc.x); acc.y = fmaf(ea, h.y, acc.y);
        }
    }
    for (int cb = beg + 2 * G; cb < end; cb += G) {          // rare tail
        int cnt = min(G, end - cb);
        int s2 = 0; float ex2 = 0.0f;
        if (r < cnt) {
            s2 = csr_src[cb + r];
            float v = ssrc_in[s2] + sdv;
            v = (v > 0.0f) ? v : NEG_SLOPE * v;
            ex2 = __expf(v);
        }
        den += ex2;
#pragma unroll
        for (int j = 0; j < G; j++) {
            int   sa = __shfl(s2, j, G);
            float ea = __shfl(ex2, j, G);
            unsigned int u = Hd[(long)sa * 16 + r];
            float2 h = __half22float2(*(__half2*)&u);
            acc.x = fmaf(ea, h.x, acc.x); acc.y = fmaf(ea, h.y, acc.y);
        }
    }
#pragma unroll
    for (int m = G / 2; m >= 1; m >>= 1) den += __shfl_xor(den, m, G);

    float inv = 1.0f / (den + 1e-16f);
    float2 b2 = ((const float2*)bias_in)[HI * 16 + r];
    float2 o;
    o.x = acc.x * inv + b2.x; o.y = acc.y * inv + b2.y;
    if (extra_out) ((float2*)(extra_out + (long)node * 64))[HI * 16 + r] = o;
    if (relu_o) { o.x = fmaxf(o.x, 0.0f); o.y = fmaxf(o.y, 0.0f); }

    if constexpr (DOUT > 0) {
        if constexpr (HI == 0) {
            ((float2*)OL)[(long)node * 16 + r] = o;          // post-relu half
        } else {
            float2 olo = ((const float2*)OL)[(long)node * 16 + r];
            constexpr int C = DOUT / 16;
            float acc2[C];
#pragma unroll
            for (int c = 0; c < C; c++) acc2[c] = 0.0f;
            const int cbase = r * C;
#pragma unroll
            for (int kb = 0; kb < 16; kb++) {
                float lx = __shfl(olo.x, kb, G), ly = __shfl(olo.y, kb, G);
                float hx = __shfl(o.x,  kb, G), hy = __shfl(o.y,  kb, G);
                const float* w0 = &sW[(2 * kb) * DOUT + cbase];
                const float* w1 = w0 + DOUT;
                const float* w2 = &sW[(32 + 2 * kb) * DOUT + cbase];
                const float* w3 = w2 + DOUT;
#pragma unroll
                for (int c = 0; c < C; c++) acc2[c] = fmaf(lx, w0[c], acc2[c]);
#pragma unroll
                for (int c = 0; c < C; c++) acc2[c] = fmaf(ly, w1[c], acc2[c]);
#pragma unroll
                for (int c = 0; c < C; c++) acc2[c] = fmaf(hx, w2[c], acc2[c]);
#pragma unroll
                for (int c = 0; c < C; c++) acc2[c] = fmaf(hy, w3[c], acc2[c]);
            }
            float ps = 0.0f, pd = 0.0f;
#pragma unroll
            for (int c = 0; c < C; c++) {
                ps = fmaf(acc2[c], a_src2[cbase + c], ps);
                pd = fmaf(acc2[c], a_dst2[cbase + c], pd);
            }
#pragma unroll
            for (int m = G / 2; m >= 1; m >>= 1) {
                ps += __shfl_xor(ps, m, G);
                pd += __shfl_xor(pd, m, G);
            }
            union { unsigned int u1; uint2 u2; __half2 h[C / 2]; } pk;
#pragma unroll
            for (int c = 0; c < C; c += 2)
                pk.h[c / 2] = __float22half2_rn(make_float2(acc2[c], acc2[c + 1]));
            if constexpr (C == 4) {       // DOUT=64 -> split planes
                __half* dp = (r < 8) ? Hh_out + (long)node * 32 + 4 * r
                                     : Hh_out + PLANE + (long)node * 32 + 4 * r - 32;
                *(uint2*)dp = pk.u2;
            } else {                      // DOUT=32 -> flat plane
                __half* dp = Hh_out + (long)node * 32 + 2 * r;
                *(unsigned int*)dp = pk.u1;
            }
            if (r == 0) { ssrc2[node] = ps; sdst2[node] = pd; }
        }
    }
}

// ===========================================================================
// DIN=32 gather (H already 3.2MB, single dispatch) + fused GEMM (DOUT=64,
// written as split planes). Structure identical to R12's gather_gemm<32,64>.
// ===========================================================================
__global__ void gather32(const __half* __restrict__ Hh_in,
                         const float* __restrict__ ssrc_in,
                         const float* __restrict__ sdst_in,
                         const int* __restrict__ offs,
                         const u16* __restrict__ csr_src,
                         const float* __restrict__ bias_in,
                         float* __restrict__ extra_out,    // [N,32] pre-relu
                         const float* __restrict__ W2,
                         const float* __restrict__ a_src2,
                         const float* __restrict__ a_dst2,
                         __half* __restrict__ Hh_out,      // split planes
                         float* __restrict__ ssrc2, float* __restrict__ sdst2) {
    const int G = 8;
    __shared__ float sW[32 * 64];
    for (int i = threadIdx.x; i < 32 * 64 / 4; i += 256)
        ((float4*)sW)[i] = ((const float4*)W2)[i];
    __syncthreads();
    const int t = threadIdx.x;
    const int node = blockIdx.x * 32 + t / G;
    const int r = t % G;
    const bool valid = (node < N_NODES);
    const int beg = valid ? offs[node] : 0;
    const int end = valid ? offs[node + 1] : 0;
    const int deg = end - beg;
    const float sdv = valid ? sdst_in[node] : 0.0f;
    const uint2* H2 = (const uint2*)Hh_in;

    int   s0 = 0, s1 = 0;
    float ex0 = 0.0f, ex1 = 0.0f;
    if (r < deg)     s0 = csr_src[beg + r];
    if (G + r < deg) s1 = csr_src[beg + G + r];
    if (r < deg) {
        float v = ssrc_in[s0] + sdv;
        v = (v > 0.0f) ? v : NEG_SLOPE * v;
        ex0 = __expf(v);
    }
    if (G + r < deg) {
        float v = ssrc_in[s1] + sdv;
        v = (v > 0.0f) ? v : NEG_SLOPE * v;
        ex1 = __expf(v);
    }
    float den = ex0 + ex1;
    float4 acc = make_float4(0.0f, 0.0f, 0.0f, 0.0f);

#pragma unroll
    for (int j = 0; j < G; j++) {
        int   sa = __shfl(s0, j, G);
        float ea = __shfl(ex0, j, G);
        union { uint2 u; __half2 h2[2]; } ua;
        ua.u = H2[(long)sa * G + r];
        float2 a0 = __half22float2(ua.h2[0]), a1 = __half22float2(ua.h2[1]);
        acc.x = fmaf(ea, a0.x, acc.x); acc.y = fmaf(ea, a0.y, acc.y);
        acc.z = fmaf(ea, a1.x, acc.z); acc.w = fmaf(ea, a1.y, acc.w);
    }
    if (deg > G) {
#pragma unroll
        for (int j = 0; j < G; j++) {
            int   sa = __shfl(s1, j, G);
            float ea = __shfl(ex1, j, G);
            union { uint2 u; __half2 h2[2]; } ua;
            ua.u = H2[(long)sa * G + r];
            float2 a0 = __half22float2(ua.h2[0]), a1 = __half22float2(ua.h2[1]);
            acc.x = fmaf(ea, a0.x, acc.x); acc.y = fmaf(ea, a0.y, acc.y);
            acc.z = fmaf(ea, a1.x, acc.z); acc.w = fmaf(ea, a1.y, acc.w);
        }
    }
    for (int cb = beg + 2 * G; cb < end; cb += G) {
        int cnt = min(G, end - cb);
        int s2 = 0; float ex2 = 0.0f;
        if (r < cnt) {
            s2 = csr_src[cb + r];
            float v = ssrc_in[s2] + sdv;
            v = (v > 0.0f) ? v : NEG_SLOPE * v;
            ex2 = __expf(v);
        }
        den += ex2;
#pragma unroll
        for (int j = 0; j < G; j++) {
            int   sa = __shfl(s2, j, G);
            float ea = __shfl(ex2, j, G);
            union { uint2 u; __half2 h2[2]; } ua;
            ua.u = H2[(long)sa * G + r];
            float2 a0 = __half22float2(ua.h2[0]), a1 = __half22float2(ua.h2[1]);
            acc.x = fmaf(ea, a0.x, acc.x); acc.y = fmaf(ea, a0.y, acc.y);
            acc.z = fmaf(ea, a1.x, acc.z); acc.w = fmaf(ea, a1.y, acc.w);
        }
    }
#pragma unroll
    for (int m = G / 2; m >= 1; m >>= 1) den += __shfl_xor(den, m, G);

    float inv = 1.0f / (den + 1e-16f);
    float4 b4 = ((const float4*)bias_in)[r];
    float4 o;
    o.x = acc.x * inv + b4.x; o.y = acc.y * inv + b4.y;
    o.z = acc.z * inv + b4.z; o.w = acc.w * inv + b4.w;
    if (valid && extra_out) ((float4*)extra_out)[(long)node * G + r] = o;  // pre-relu
    o.x = fmaxf(o.x, 0.0f); o.y = fmaxf(o.y, 0.0f);
    o.z = fmaxf(o.z, 0.0f); o.w = fmaxf(o.w, 0.0f);

    // fused GEMM: 32 -> 64, C=8 channels per lane
    float acc2[8];
#pragma unroll
    for (int c = 0; c < 8; c++) acc2[c] = 0.0f;
    const int cbase = r * 8;
#pragma unroll
    for (int kb = 0; kb < G; kb++) {
        float4 o4;
        o4.x = __shfl(o.x, kb, G);
        o4.y = __shfl(o.y, kb, G);
        o4.z = __shfl(o.z, kb, G);
        o4.w = __shfl(o.w, kb, G);
        const float* wr = &sW[(4 * kb) * 64 + cbase];
#pragma unroll
        for (int c = 0; c < 8; c++) acc2[c] = fmaf(o4.x, wr[c], acc2[c]);
        wr += 64;
#pragma unroll
        for (int c = 0; c < 8; c++) acc2[c] = fmaf(o4.y, wr[c], acc2[c]);
        wr += 64;
#pragma unroll
        for (int c = 0; c < 8; c++) acc2[c] = fmaf(o4.z, wr[c], acc2[c]);
        wr += 64;
#pragma unroll
        for (int c = 0; c < 8; c++) acc2[c] = fmaf(o4.w, wr[c], acc2[c]);
    }
    float ps = 0.0f, pd = 0.0f;
#pragma unroll
    for (int c = 0; c < 8; c++) {
        ps = fmaf(acc2[c], a_src2[cbase + c], ps);
        pd = fmaf(acc2[c], a_dst2[cbase + c], pd);
    }
#pragma unroll
    for (int m = G / 2; m >= 1; m >>= 1) {
        ps += __shfl_xor(ps, m, G);
        pd += __shfl_xor(pd, m, G);
    }
    if (valid) {
        union { uint4 u4; __half2 h[4]; } pk;
#pragma unroll
        for (int c = 0; c < 8; c += 2)
            pk.h[c / 2] = __float22half2_rn(make_float2(acc2[c], acc2[c + 1]));
        __half* dp = (r < 4) ? Hh_out + (long)node * 32 + 8 * r
                             : Hh_out + PLANE + (long)node * 32 + 8 * r - 32;
        *(uint4*)dp = pk.u4;
        if (r == 0) { ssrc2[node] = ps; sdst2[node] = pd; }
    }
}

extern "C" void kernel_launch(void* const* d_in, const int* in_sizes, int n_in,
                              void* d_out, int out_size, void* d_ws, size_t ws_size,
                              hipStream_t stream) {
    const float* x  = (const float*)d_in[0];
    const int*   ei = (const int*)d_in[1];

    const float* w1  = (const float*)d_in[2];
    const float* as1 = (const float*)d_in[3];
    const float* ad1 = (const float*)d_in[4];
    const float* b1  = (const float*)d_in[5];
    const float* w2  = (const float*)d_in[6];
    const float* as2 = (const float*)d_in[7];
    const float* ad2 = (const float*)d_in[8];
    const float* b2  = (const float*)d_in[9];
    const float* w3  = (const float*)d_in[10];
    const float* as3 = (const float*)d_in[11];
    const float* ad3 = (const float*)d_in[12];
    const float* b3  = (const float*)d_in[13];
    const float* w4  = (const float*)d_in[14];
    const float* as4 = (const float*)d_in[15];
    const float* ad4 = (const float*)d_in[16];
    const float* b4  = (const float*)d_in[17];

    float* out_final = (float*)d_out;                 // [N, 64]
    float* out_h     = (float*)d_out + N_NODES * 64;  // [N, 32] (layer2 pre-relu)

    // workspace layout
    float* ws    = (float*)d_ws;
    __half* Hh_a = (__half*)ws;                 // N*64 halves (two planes)
    __half* Hh_b = (__half*)(ws + N_NODES * 32);
    float* SS_a  = ws + 2 * N_NODES * 32;       // N
    float* SD_a  = SS_a + N_NODES;              // N
    float* SS_b  = SD_a + N_NODES;              // N
    float* SD_b  = SS_b + N_NODES;              // N
    float* OL    = SD_b + N_NODES;              // N*32 fp32 half-output
    int* deg     = (int*)(OL + N_NODES * 32);   // N ints
    u16* rank    = (u16*)(deg + N_NODES);       // E_TOT u16
    int* offs    = (int*)(rank + E_TOT);        // N+1 ints
    u16* csr_src = (u16*)(offs + N_NODES + 1);  // E_TOT u16
    int* bsum    = (int*)(csr_src + E_TOT);     // NB_SCAN ints

    const int* src = ei;                // edge_index row 0
    const int* dst = ei + N_EDGES;      // edge_index row 1

    // --- build CSR by dst (once; shared by all 4 layers) ---
    csr_init<<<(N_NODES + 255) / 256, 256, 0, stream>>>(deg);
    csr_degree<<<(E_TOT + 255) / 256, 256, 0, stream>>>(dst, deg, rank);
    scan_p1<<<NB_SCAN, 1024, 0, stream>>>(deg, bsum);
    scan_p3<<<NB_SCAN, 1024, 0, stream>>>(deg, bsum, offs);
    csr_fill<<<(E_TOT + 255) / 256, 256, 0, stream>>>(src, dst, rank, offs, csr_src);

    // --- layer-1 GEMM, then split-channel gather stages ---
    gemm_proj<<<(N_NODES + 15) / 16, 256, 0, stream>>>(
        x, w1, as1, ad1, Hh_a, SS_a, SD_a);

    const int GB64 = N_NODES / 16;              // 3125, exact
    const int GB32 = (N_NODES + 31) / 32;

    // layer 1 aggregate (+b1, relu) -> gemm W2(64->32) -> Hh_b flat
    gather64<32, 0><<<GB64, 256, 0, stream>>>(
        Hh_a, SS_a, SD_a, offs, csr_src, b1, 1, nullptr, OL,
        w2, as2, ad2, Hh_b, SS_b, SD_b);
    gather64<32, 1><<<GB64, 256, 0, stream>>>(
        Hh_a + PLANE, SS_a, SD_a, offs, csr_src, b1, 1, nullptr, OL,
        w2, as2, ad2, Hh_b, SS_b, SD_b);
    // layer 2 aggregate (+b2) -> out_h pre-relu, relu -> gemm W3(32->64) split
    gather32<<<GB32, 256, 0, stream>>>(
        Hh_b, SS_b, SD_b, offs, csr_src, b2, out_h,
        w3, as3, ad3, Hh_a, SS_a, SD_a);
    // layer 3 aggregate (+b3, relu) -> gemm W4(64->64) split
    gather64<64, 0><<<GB64, 256, 0, stream>>>(
        Hh_a, SS_a, SD_a, offs, csr_src, b3, 1, nullptr, OL,
        w4, as4, ad4, Hh_b, SS_b, SD_b);
    gather64<64, 1><<<GB64, 256, 0, stream>>>(
        Hh_a + PLANE, SS_a, SD_a, offs, csr_src, b3, 1, nullptr, OL,
        w4, as4, ad4, Hh_b, SS_b, SD_b);
    // layer 4 aggregate (+b4, no relu) -> out_final
    gather64<0, 0><<<GB64, 256, 0, stream>>>(
        Hh_b, SS_b, SD_b, offs, csr_src, b4, 0, out_final, nullptr,
        nullptr, nullptr, nullptr, nullptr, nullptr, nullptr);
    gather64<0, 1><<<GB64, 256, 0, stream>>>(
        Hh_b + PLANE, SS_b, SD_b, offs, csr_src, b4, 0, out_final, nullptr,
        nullptr, nullptr, nullptr, nullptr, nullptr, nullptr);
}